// Round 2
// baseline (389.173 us; speedup 1.0000x reference)
//
#include <hip/hip_runtime.h>
#include <math.h>

#define NB   1024
#define NG   2000
#define NGS  25
#define KP   2048   // K padded to multiple of 64 for MFMA GEMM1
#define NH1  1024
#define NH2  512
#define NC   10
#define EPSV 1e-5f
#define GPB  200    // gene groups per block

// R8: discrimination round. (a) prep: gw chunk staged to LDS coalesced
// (removes the 100B-stride gw scatter, ~1 GB L2 -> 205 MB); (b) gemm1:
// BK 64->128 -- halves barrier count, doubles MFMA per barrier, same
// conflict-free pitch class (132 shorts == 2 mod 32 dw). If dur_us moves
// <5 us again, the ~240 us residual is the harness's timed 800 MB poison
// fills (2 x ~119 us) and we are at the practical floor.
// R7: residual head into prep (partials), final Wout via LDS, gemm2 BN1
// tables in LDS. R5/R6 notes: no cooperative fusion; t1 stays fp32.

typedef __attribute__((ext_vector_type(8)))  __bf16 bf16x8;
typedef __attribute__((ext_vector_type(4)))  float  f32x4;
typedef __attribute__((ext_vector_type(16))) float  f32x16;
typedef __attribute__((ext_vector_type(8)))  unsigned short u16x8;
typedef __attribute__((ext_vector_type(4)))  unsigned short u16x4;

__device__ __forceinline__ unsigned short f2bf(float f) {
  union { float f; unsigned u; } v; v.f = f;
  return (unsigned short)((v.u + 0x7fffu + ((v.u >> 16) & 1u)) >> 16);
}
__device__ __forceinline__ float bf2f(unsigned short b) {
  union { unsigned u; float f; } v; v.u = ((unsigned)b) << 16;
  return v.f;
}

// ---------------------------------------------------------------------------
// Prep + gene dispatch. grid (1024, 11):
//   y < 10 : gene layer block (batch row b = x, group-chunk y) + residual
//            partial rp[b][y][0..9] (Wres slice staged in reused LDS)
//   y == 10: x<512 -> convT W1 tile; x in [512,640) -> convT W2 tile;
//            x==640 -> zero BN stat accumulators; else idle.
// LDS 40 KB (xs 20 + gws 20) -> 4 blocks/CU, 16 waves/CU: ample for HBM
// streaming (need ~9 KB in flight per CU at 6.3 TB/s, have ~80 KB).
// ---------------------------------------------------------------------------
__global__ __launch_bounds__(256) void prep_kernel(
    const float* __restrict__ x, const float* __restrict__ gw,
    const float* __restrict__ gb, unsigned short* __restrict__ g_bf,
    const float* __restrict__ W1, unsigned short* __restrict__ W1bT,
    const float* __restrict__ W2, unsigned short* __restrict__ W2bT,
    const float* __restrict__ Wres, float* __restrict__ rp,
    float* __restrict__ stats) {
  __shared__ __attribute__((aligned(16))) char smem[2 * GPB * NGS * 4]; // 40 KB
  __shared__ float rred[4][NC];
  int t = threadIdx.x;

  if (blockIdx.y < 10) {                 // ---- gene path
    float* xs  = (float*)smem;
    float* gws = (float*)(smem + GPB * NGS * 4);
    int b = blockIdx.x;
    int blk = blockIdx.y;
    const float4* src  = (const float4*)(x + (size_t)b * (NG * NGS) + blk * (GPB * NGS));
    const float4* gsrc = (const float4*)(gw + (size_t)blk * (GPB * NGS));
    float4* dst  = (float4*)xs;
    float4* gdst = (float4*)gws;
    for (int i = t; i < (GPB * NGS) / 4; i += 256) {
      dst[i]  = src[i];
      gdst[i] = gsrc[i];
    }
    __syncthreads();
    float g = 0.f;                        // relu'd gene value (fp32)
    if (t < GPB) {
      int gi = blk * GPB + t;
      const float* wp = gws + t * NGS;    // LDS, stride-25: 2 lanes/bank, free
      const float* xp = xs + t * NGS;
      float acc = 0.f;
#pragma unroll
      for (int k = 0; k < NGS; ++k) acc = fmaf(xp[k], wp[k], acc);
      g = fmaxf(acc + gb[gi], 0.f);
      g_bf[(size_t)b * KP + gi] = f2bf(g);
    } else if (blk == 9 && t < GPB + (KP - NG)) {
      g_bf[(size_t)b * KP + NG + (t - GPB)] = 0;   // zero-pad k 2000..2047
    }
    __syncthreads();                      // xs free now
    // residual head partial: stage Wres rows [blk*200, +200) (8 KB) coalesced
    float* ws = xs;
    const float4* wsrc = (const float4*)(Wres + (size_t)blk * (GPB * NC));
    float4* wdst = (float4*)ws;
    for (int i = t; i < (GPB * NC) / 4; i += 256) wdst[i] = wsrc[i];
    __syncthreads();
    float r[NC];
#pragma unroll
    for (int c = 0; c < NC; ++c) r[c] = (t < GPB) ? g * ws[t * NC + c] : 0.f;
    int lane = t & 63, wave = t >> 6;
#pragma unroll
    for (int c = 0; c < NC; ++c) {
      float v = r[c];
      for (int off = 32; off > 0; off >>= 1) v += __shfl_down(v, off, 64);
      if (lane == 0) rred[wave][c] = v;
    }
    __syncthreads();
    if (t < NC)
      rp[(size_t)b * (10 * NC) + blk * NC + t] =
          rred[0][t] + rred[1][t] + rred[2][t] + rred[3][t];
    return;
  }

  // ---- prep path (y == 10)
  int bx = blockIdx.x;
  if (bx == 640) {                       // zero BN stats (3072 floats)
    for (int i = t; i < 3072; i += 256) stats[i] = 0.f;
    return;
  }
  const float* src; unsigned short* dst; int K, N, Kpad, k0, n0;
  if (bx < 512)      { src = W1; dst = W1bT; K = NG;  N = NH1; Kpad = KP;
                       k0 = (bx & 31) * 64; n0 = (bx >> 5) * 64; }
  else if (bx < 640) { int xi = bx - 512;
                       src = W2; dst = W2bT; K = NH1; N = NH2; Kpad = NH1;
                       k0 = (xi & 15) * 64; n0 = (xi >> 4) * 64; }
  else return;

  unsigned short (*ts)[72] = (unsigned short (*)[72])smem;   // 64x72 = 9.2 KB
  int c4 = (t & 15) * 4;
  int r  = t >> 4;
  for (int rr = r; rr < 64; rr += 16) {
    int k = k0 + rr;
    float4 v = make_float4(0.f, 0.f, 0.f, 0.f);
    if (k < K) v = *(const float4*)&src[(size_t)k * N + n0 + c4];
    ts[rr][c4 + 0] = f2bf(v.x); ts[rr][c4 + 1] = f2bf(v.y);
    ts[rr][c4 + 2] = f2bf(v.z); ts[rr][c4 + 3] = f2bf(v.w);
  }
  __syncthreads();
  int rr8 = (t & 7) * 8;
  int cc  = t >> 3;
  for (int c = cc; c < 64; c += 32) {
    u16x8 val;
#pragma unroll
    for (int i = 0; i < 8; ++i) val[i] = ts[rr8 + i][c];
    *(u16x8*)&dst[(size_t)(n0 + c) * Kpad + k0 + rr8] = val;
  }
}

// ---------------------------------------------------------------------------
// GEMM1: t1(fp32) = A(bf16)[M][Kp] * Bt(bf16)[N][Kp]^T, fused BN1 stats.
// 32x64 block tile (grid 512 = 2 blocks/CU), 32x32x16 MFMA, BK=128 (R8):
// 16 K-iters, 4 MFMA + 8 ds_read_b128 per wave per iter. 4 waves:
// h = n-half (32 cols), p = k-phase (64 of the 128-col K-tile). k-phases
// combine through a stride-17 LDS buffer (conflict-free scalar f32).
// Pitch 132 shorts = 66 dw == 2 mod 32 -> 2 lanes/bank ds_reads (free).
// ---------------------------------------------------------------------------
__global__ __launch_bounds__(256) void gemm1_kernel(
    const unsigned short* __restrict__ A,    // [M][Kp]
    const unsigned short* __restrict__ Bt,   // [N][Kp]
    float* __restrict__ C, float* __restrict__ sum, float* __restrict__ sq,
    int M, int N, int Kp) {
  __shared__ unsigned short As[32][132];
  __shared__ unsigned short Bs[64][132];
  __shared__ float ebuf[2 * 64 * 17];        // k-phase combine, stride 17
  int t = threadIdx.x;
  int m0 = blockIdx.y * 32, n0 = blockIdx.x * 64;
  int wave = t >> 6, lane = t & 63;
  int h = wave & 1;            // n-half
  int p = wave >> 1;           // k-phase
  int l31 = lane & 31, l5 = lane >> 5;
  int srow = t >> 3, skc = (t & 7) * 8;      // staging: 32 rows x 64 cols x2

  f32x16 acc;
#pragma unroll
  for (int q = 0; q < 16; ++q) acc[q] = 0.f;

  const unsigned short* Ap = A + (size_t)(m0 + srow) * Kp + skc;
  const unsigned short* Bp = Bt + (size_t)(n0 + srow) * Kp + skc;
  size_t rstep = 32 * (size_t)Kp;

  u16x8 pa0 = *(const u16x8*)(Ap);
  u16x8 pa1 = *(const u16x8*)(Ap + 64);
  u16x8 pb0 = *(const u16x8*)(Bp);
  u16x8 pb1 = *(const u16x8*)(Bp + 64);
  u16x8 pb2 = *(const u16x8*)(Bp + rstep);
  u16x8 pb3 = *(const u16x8*)(Bp + rstep + 64);

  for (int k0 = 0; k0 < Kp; k0 += 128) {
    *(u16x8*)&As[srow][skc]           = pa0;
    *(u16x8*)&As[srow][skc + 64]      = pa1;
    *(u16x8*)&Bs[srow][skc]           = pb0;
    *(u16x8*)&Bs[srow][skc + 64]      = pb1;
    *(u16x8*)&Bs[srow + 32][skc]      = pb2;
    *(u16x8*)&Bs[srow + 32][skc + 64] = pb3;
    __syncthreads();
    if (k0 + 128 < Kp) {
      pa0 = *(const u16x8*)(Ap + k0 + 128);
      pa1 = *(const u16x8*)(Ap + k0 + 192);
      pb0 = *(const u16x8*)(Bp + k0 + 128);
      pb1 = *(const u16x8*)(Bp + k0 + 192);
      pb2 = *(const u16x8*)(Bp + k0 + 128 + rstep);
      pb3 = *(const u16x8*)(Bp + k0 + 192 + rstep);
    }
    int kb = p * 64 + l5 * 8;
#pragma unroll
    for (int s = 0; s < 4; ++s) {
      bf16x8 av = *(const bf16x8*)&As[l31][kb + s * 16];
      bf16x8 bv = *(const bf16x8*)&Bs[h * 32 + l31][kb + s * 16];
      acc = __builtin_amdgcn_mfma_f32_32x32x16_bf16(av, bv, acc, 0, 0, 0);
    }
    __syncthreads();
  }

  // combine k-phases: p=1 publishes, p=0 adds + stores + stats
  float* eb = ebuf + (size_t)(h * 64 + lane) * 17;
  if (p == 1) {
#pragma unroll
    for (int r = 0; r < 16; ++r) eb[r] = acc[r];
  }
  __syncthreads();
  if (p == 0) {
    float s = 0.f, ss = 0.f;
#pragma unroll
    for (int r = 0; r < 16; ++r) {
      float v = acc[r] + eb[r];
      // C/D 32x32: col=lane&31, row=(r&3)+8*(r>>2)+4*(lane>>5)
      int row = m0 + (r & 3) + 8 * (r >> 2) + 4 * l5;
      C[(size_t)row * N + n0 + h * 32 + l31] = v;
      s += v;
      ss = fmaf(v, v, ss);
    }
    s  += __shfl_down(s, 32, 64);
    ss += __shfl_down(ss, 32, 64);
    if (lane < 32) {
      atomicAdd(&sum[n0 + h * 32 + lane], s);
      atomicAdd(&sq[n0 + h * 32 + lane], ss);
    }
  }
}

// ---------------------------------------------------------------------------
// GEMM2: A = t1 fp32, BN1+ReLU applied during LDS staging (-> bf16);
// B = W2bT bf16. Fused BN2 stats. 32x32 tile (grid 512 = 2 blocks/CU),
// 4 waves each 16x16. BN1 scale/shift precomputed once per block into
// LDS tables (broadcast reads, conflict-free).
// ---------------------------------------------------------------------------
__global__ __launch_bounds__(256) void gemm2_kernel(
    const float* __restrict__ A,             // [M][Kp] fp32 (t1, pre-BN)
    const unsigned short* __restrict__ Bt,   // [N][Kp] bf16
    float* __restrict__ C, const float* __restrict__ sum1,
    const float* __restrict__ sq1, const float* __restrict__ gam1,
    const float* __restrict__ bet1, float* __restrict__ sum2,
    float* __restrict__ sq2, int M, int N, int Kp) {
  __shared__ unsigned short As[32][72];
  __shared__ unsigned short Bs[32][72];
  __shared__ float sc1s[NH1], sh1s[NH1];     // 8 KB BN1 coef tables
  int t = threadIdx.x;
  int m0 = blockIdx.y * 32, n0 = blockIdx.x * 32;
  int wave = t >> 6, lane = t & 63;
  int wm = (wave >> 1) * 16, wn = (wave & 1) * 16;
  int fm = lane & 15, fk = (lane >> 4) * 8;
  int srow = t >> 3, skc = (t & 7) * 8;    // srow 0..31

  for (int k = t; k < Kp; k += 256) {      // once per block: 4 rsqrt/thread
    float mu  = sum1[k] * (1.f / NB);
    float var = sq1[k] * (1.f / NB) - mu * mu;
    float scv = gam1[k] * rsqrtf(var + EPSV);
    sc1s[k] = scv;
    sh1s[k] = fmaf(-mu, scv, bet1[k]);
  }

  f32x4 acc = (f32x4){0.f, 0.f, 0.f, 0.f};

  const float* Ap = A + (size_t)(m0 + srow) * Kp + skc;
  const unsigned short* Bp = Bt + (size_t)(n0 + srow) * Kp + skc;

  f32x4 pa0 = *(const f32x4*)(Ap);
  f32x4 pa1 = *(const f32x4*)(Ap + 4);
  u16x8 pb0 = *(const u16x8*)(Bp);
  __syncthreads();                          // coef tables ready

  for (int k0 = 0; k0 < Kp; k0 += 64) {
    // BN1 scale/shift from LDS (8 distinct 16B groups/wave -> broadcast)
    f32x4 scl = *(const f32x4*)&sc1s[k0 + skc];
    f32x4 sch = *(const f32x4*)&sc1s[k0 + skc + 4];
    f32x4 shl = *(const f32x4*)&sh1s[k0 + skc];
    f32x4 shh = *(const f32x4*)&sh1s[k0 + skc + 4];
    u16x8 a0;
#pragma unroll
    for (int i = 0; i < 4; ++i) {
      a0[i]     = f2bf(fmaxf(fmaf(pa0[i], scl[i], shl[i]), 0.f));
      a0[i + 4] = f2bf(fmaxf(fmaf(pa1[i], sch[i], shh[i]), 0.f));
    }
    *(u16x8*)&As[srow][skc] = a0;
    *(u16x8*)&Bs[srow][skc] = pb0;
    __syncthreads();
    if (k0 + 64 < Kp) {
      pa0 = *(const f32x4*)(Ap + k0 + 64);
      pa1 = *(const f32x4*)(Ap + k0 + 64 + 4);
      pb0 = *(const u16x8*)(Bp + k0 + 64);
    }
#pragma unroll
    for (int s = 0; s < 2; ++s) {
      bf16x8 af = *(const bf16x8*)&As[wm + fm][s * 32 + fk];
      bf16x8 bf = *(const bf16x8*)&Bs[wn + fm][s * 32 + fk];
      acc = __builtin_amdgcn_mfma_f32_16x16x32_bf16(af, bf, acc, 0, 0, 0);
    }
    __syncthreads();
  }

  int crow = (lane >> 4) * 4, ccol = lane & 15;
  float s = 0.f, ss = 0.f;
#pragma unroll
  for (int r = 0; r < 4; ++r) {
    float v = acc[r];
    int m = m0 + wm + crow + r;
    int n = n0 + wn + ccol;
    C[(size_t)m * N + n] = v;
    s += v;
    ss = fmaf(v, v, ss);
  }
  s  += __shfl_down(s, 32, 64);  s  += __shfl_down(s, 16, 64);
  ss += __shfl_down(ss, 32, 64); ss += __shfl_down(ss, 16, 64);
  if (lane < 16) {
    atomicAdd(&sum2[n0 + wn + lane], s);
    atomicAdd(&sq2[n0 + wn + lane], ss);
  }
}

// ---------------------------------------------------------------------------
// Final: BN2(inline)+ReLU on t2 row, main head from LDS-staged Wout,
// residual from prep's partials, softmax. Block per row, all 256 threads.
// ---------------------------------------------------------------------------
__global__ __launch_bounds__(256) void final_kernel(
    const float* __restrict__ t2, const float* __restrict__ sum2,
    const float* __restrict__ sq2, const float* __restrict__ gam2,
    const float* __restrict__ bet2, const float* __restrict__ rp,
    const float* __restrict__ Wout, const float* __restrict__ bout,
    const float* __restrict__ bres, float* __restrict__ out) {
  __shared__ __attribute__((aligned(16))) float wl[NH2 * NC];   // 20 KB
  __shared__ float red[4][NC];
  __shared__ float logits[NC];
  int b = blockIdx.x;
  int t = threadIdx.x;

  // stage Wout coalesced: 1280 float4 / 256 threads = 5 each
  const float4* wsrc = (const float4*)Wout;
  float4* wdst = (float4*)wl;
#pragma unroll
  for (int i = 0; i < (NH2 * NC / 4) / 256; ++i)
    wdst[t + i * 256] = wsrc[t + i * 256];
  __syncthreads();

  float acc[NC] = {};
#pragma unroll
  for (int half = 0; half < 2; ++half) {
    int h = t + half * 256;
    float raw = t2[(size_t)b * NH2 + h];
    float mu  = sum2[h] * (1.f / NB);
    float var = sq2[h] * (1.f / NB) - mu * mu;
    float scv = gam2[h] * rsqrtf(var + EPSV);
    float hr  = fmaxf(fmaf(raw, scv, fmaf(-mu, scv, bet2[h])), 0.f);
    const float* wrow = &wl[h * NC];
#pragma unroll
    for (int c = 0; c < NC; ++c) acc[c] = fmaf(hr, wrow[c], acc[c]);
  }

  int lane = t & 63, wave = t >> 6;
#pragma unroll
  for (int c = 0; c < NC; ++c) {
    float v = acc[c];
    for (int off = 32; off > 0; off >>= 1) v += __shfl_down(v, off, 64);
    if (lane == 0) red[wave][c] = v;
  }
  __syncthreads();
  if (t < NC) {
    float v = red[0][t] + red[1][t] + red[2][t] + red[3][t] + bout[t] + bres[t];
    const float* rpb = rp + (size_t)b * (10 * NC);
#pragma unroll
    for (int kb = 0; kb < 10; ++kb) v += rpb[kb * NC + t];
    logits[t] = v;
  }
  __syncthreads();
  if (t == 0) {
    float mx = logits[0];
#pragma unroll
    for (int c = 1; c < NC; ++c) mx = fmaxf(mx, logits[c]);
    float e[NC], s = 0.f;
#pragma unroll
    for (int c = 0; c < NC; ++c) { e[c] = expf(logits[c] - mx); s += e[c]; }
    float inv = 1.f / s;
#pragma unroll
    for (int c = 0; c < NC; ++c) out[(size_t)b * NC + c] = e[c] * inv;
  }
}

// ---------------------------------------------------------------------------
extern "C" void kernel_launch(void* const* d_in, const int* in_sizes, int n_in,
                              void* d_out, int out_size, void* d_ws, size_t ws_size,
                              hipStream_t stream) {
  const float* x      = (const float*)d_in[0];
  const float* gw     = (const float*)d_in[1];
  const float* gb     = (const float*)d_in[2];
  const float* W1     = (const float*)d_in[3];
  const float* gamma1 = (const float*)d_in[5];
  const float* beta1  = (const float*)d_in[6];
  const float* W2     = (const float*)d_in[7];
  const float* gamma2 = (const float*)d_in[9];
  const float* beta2  = (const float*)d_in[10];
  const float* Wout   = (const float*)d_in[11];
  const float* bout   = (const float*)d_in[12];
  const float* Wres   = (const float*)d_in[13];
  const float* bres   = (const float*)d_in[14];
  float* out = (float*)d_out;

  char* p = (char*)d_ws;
  unsigned short* g_bf = (unsigned short*)p; p += (size_t)NB * KP * 2;    // 4 MB
  unsigned short* W1bT = (unsigned short*)p; p += (size_t)NH1 * KP * 2;   // 4 MB
  unsigned short* W2bT = (unsigned short*)p; p += (size_t)NH2 * NH1 * 2;  // 1 MB
  float* t1 = (float*)p; p += (size_t)NB * NH1 * 4;                       // 4 MB
  float* t2 = (float*)p; p += (size_t)NB * NH2 * 4;                       // 2 MB
  float* stats = (float*)p; p += 3072 * 4;
  float* rp = (float*)p; p += (size_t)NB * 10 * NC * 4;                   // 400 KB
  float* sum1 = stats, *sq1 = stats + 1024, *sum2 = stats + 2048, *sq2 = stats + 2560;

  // gene + residual partials + weight-transpose + stats-zero in one dispatch
  prep_kernel<<<dim3(NB, 11), 256, 0, stream>>>(x, gw, gb, g_bf,
                                                W1, W1bT, W2, W2bT,
                                                Wres, rp, stats);

  gemm1_kernel<<<dim3(NH1 / 64, NB / 32), 256, 0, stream>>>(
      g_bf, W1bT, t1, sum1, sq1, NB, NH1, KP);

  gemm2_kernel<<<dim3(NH2 / 32, NB / 32), 256, 0, stream>>>(
      t1, W2bT, t2, sum1, sq1, gamma1, beta1, sum2, sq2, NB, NH2, NH1);

  final_kernel<<<NB, 256, 0, stream>>>(t2, sum2, sq2, gamma2, beta2, rp,
                                       Wout, bout, bres, out);
}

// Round 3
// 360.486 us; speedup vs baseline: 1.0796x; 1.0796x over previous
//
#include <hip/hip_runtime.h>
#include <math.h>

#define NB   1024
#define NG   2000
#define NGS  25
#define KP   2048   // K padded to multiple of 64 for MFMA GEMM1
#define NH1  1024
#define NH2  512
#define NC   10
#define EPSV 1e-5f
#define GPB  200    // gene groups per block
#define RB   8      // batch rows per gene block (R9)

// R9: prep redesigned -- gene block owns (gene-chunk, RB=8 rows). gw chunk
// staged coalesced ONCE -> registers (25/thread); Wres staged ONCE to LDS;
// 8 rounds of {x-row stage -> dot -> residual partial}. Kills the per-row
// gw re-fetch (R7: L1 tag-serialized scatter ~83us; R8: 205 MB redundant
// L2 bulk, +27us) and per-row Wres stage. LDS 28.2 KB -> 5 blocks/CU.
// gemm1 reverted to R5/R7-validated BK=64 (BK=128 measured neutral).
// Timed-region model: ~240us harness poison fills (fixed) + kernels.

typedef __attribute__((ext_vector_type(8)))  __bf16 bf16x8;
typedef __attribute__((ext_vector_type(4)))  float  f32x4;
typedef __attribute__((ext_vector_type(16))) float  f32x16;
typedef __attribute__((ext_vector_type(8)))  unsigned short u16x8;
typedef __attribute__((ext_vector_type(4)))  unsigned short u16x4;

__device__ __forceinline__ unsigned short f2bf(float f) {
  union { float f; unsigned u; } v; v.f = f;
  return (unsigned short)((v.u + 0x7fffu + ((v.u >> 16) & 1u)) >> 16);
}
__device__ __forceinline__ float bf2f(unsigned short b) {
  union { unsigned u; float f; } v; v.u = ((unsigned)b) << 16;
  return v.f;
}

// ---------------------------------------------------------------------------
// Prep + gene dispatch. grid (128, 16):
//   y < 10 : gene block: gene-chunk y (200 groups), rows [x*RB, x*RB+RB)
//   y >= 10: px = (y-10)*128 + x:
//            px<512 -> convT W1 tile; px in [512,640) -> convT W2 tile;
//            px==640 -> zero BN stat accumulators; else idle.
// ---------------------------------------------------------------------------
__global__ __launch_bounds__(256) void prep_kernel(
    const float* __restrict__ x, const float* __restrict__ gw,
    const float* __restrict__ gb, unsigned short* __restrict__ g_bf,
    const float* __restrict__ W1, unsigned short* __restrict__ W1bT,
    const float* __restrict__ W2, unsigned short* __restrict__ W2bT,
    const float* __restrict__ Wres, float* __restrict__ rp,
    float* __restrict__ stats) {
  __shared__ __attribute__((aligned(16))) float xs[GPB * NGS];   // 20 KB
  __shared__ __attribute__((aligned(16))) float ws[GPB * NC];    // 8 KB
  __shared__ float rred[4][NC];
  int t = threadIdx.x;

  if (blockIdx.y < 10) {                 // ---- gene path
    int blk = blockIdx.y;
    int b0 = blockIdx.x * RB;
    // stage gw chunk (20 KB) coalesced into xs, then copy to registers
    const float4* gsrc = (const float4*)(gw + (size_t)blk * (GPB * NGS));
    float4* xd = (float4*)xs;
    for (int i = t; i < (GPB * NGS) / 4; i += 256) xd[i] = gsrc[i];
    // stage Wres chunk (8 KB) coalesced, persistent
    const float4* wsrc = (const float4*)(Wres + (size_t)blk * (GPB * NC));
    float4* wd = (float4*)ws;
    for (int i = t; i < (GPB * NC) / 4; i += 256) wd[i] = wsrc[i];
    __syncthreads();
    float gwr[NGS];                       // per-thread gene weights
    float gbv = 0.f;
    int gi = blk * GPB + t;
    if (t < GPB) {
#pragma unroll
      for (int k = 0; k < NGS; ++k) gwr[k] = xs[t * NGS + k];
      gbv = gb[gi];
    }
    __syncthreads();                      // xs free for x rows
    int lane = t & 63, wave = t >> 6;
    for (int r = 0; r < RB; ++r) {
      int b = b0 + r;
      const float4* src = (const float4*)(x + (size_t)b * (NG * NGS) + blk * (GPB * NGS));
      for (int i = t; i < (GPB * NGS) / 4; i += 256) xd[i] = src[i];
      __syncthreads();
      float g = 0.f;
      if (t < GPB) {
        float acc = 0.f;
        const float* xp = xs + t * NGS;   // stride-25: 2 lanes/bank, free
#pragma unroll
        for (int k = 0; k < NGS; ++k) acc = fmaf(xp[k], gwr[k], acc);
        g = fmaxf(acc + gbv, 0.f);
        g_bf[(size_t)b * KP + gi] = f2bf(g);
      } else if (blk == 9 && t < GPB + (KP - NG)) {
        g_bf[(size_t)b * KP + NG + (t - GPB)] = 0;   // zero-pad k 2000..2047
      }
      // residual partial for row b
#pragma unroll
      for (int c = 0; c < NC; ++c) {
        float v = (t < GPB) ? g * ws[t * NC + c] : 0.f;
        for (int off = 32; off > 0; off >>= 1) v += __shfl_down(v, off, 64);
        if (lane == 0) rred[wave][c] = v;
      }
      __syncthreads();
      if (t < NC)
        rp[(size_t)b * (10 * NC) + blk * NC + t] =
            rred[0][t] + rred[1][t] + rred[2][t] + rred[3][t];
      __syncthreads();                    // rred/xs safe before next round
    }
    return;
  }

  // ---- prep path (y >= 10)
  int px = (blockIdx.y - 10) * 128 + blockIdx.x;
  if (px == 640) {                       // zero BN stats (3072 floats)
    for (int i = t; i < 3072; i += 256) stats[i] = 0.f;
    return;
  }
  if (px > 640) return;
  const float* src; unsigned short* dst; int K, N, Kpad, k0, n0;
  if (px < 512)      { src = W1; dst = W1bT; K = NG;  N = NH1; Kpad = KP;
                       k0 = (px & 31) * 64; n0 = (px >> 5) * 64; }
  else               { int xi = px - 512;
                       src = W2; dst = W2bT; K = NH1; N = NH2; Kpad = NH1;
                       k0 = (xi & 15) * 64; n0 = (xi >> 4) * 64; }

  unsigned short (*ts)[72] = (unsigned short (*)[72])xs;   // 64x72 = 9.2 KB
  int c4 = (t & 15) * 4;
  int r  = t >> 4;
  for (int rr = r; rr < 64; rr += 16) {
    int k = k0 + rr;
    float4 v = make_float4(0.f, 0.f, 0.f, 0.f);
    if (k < K) v = *(const float4*)&src[(size_t)k * N + n0 + c4];
    ts[rr][c4 + 0] = f2bf(v.x); ts[rr][c4 + 1] = f2bf(v.y);
    ts[rr][c4 + 2] = f2bf(v.z); ts[rr][c4 + 3] = f2bf(v.w);
  }
  __syncthreads();
  int rr8 = (t & 7) * 8;
  int cc  = t >> 3;
  for (int c = cc; c < 64; c += 32) {
    u16x8 val;
#pragma unroll
    for (int i = 0; i < 8; ++i) val[i] = ts[rr8 + i][c];
    *(u16x8*)&dst[(size_t)(n0 + c) * Kpad + k0 + rr8] = val;
  }
}

// ---------------------------------------------------------------------------
// GEMM1: t1(fp32) = A(bf16)[M][Kp] * Bt(bf16)[N][Kp]^T, fused BN1 stats.
// 32x64 block tile (grid 512 = 2 blocks/CU), 32x32x16 MFMA. 4 waves:
// h = n-half (32 cols), p = k-phase (32 of the 64-col K-tile). k-phases
// combine through a stride-17 LDS buffer (conflict-free scalar f32).
// ---------------------------------------------------------------------------
__global__ __launch_bounds__(256) void gemm1_kernel(
    const unsigned short* __restrict__ A,    // [M][Kp]
    const unsigned short* __restrict__ Bt,   // [N][Kp]
    float* __restrict__ C, float* __restrict__ sum, float* __restrict__ sq,
    int M, int N, int Kp) {
  __shared__ unsigned short As[32][68];      // pitch 34 dw (== 2 mod 32)
  __shared__ unsigned short Bs[64][68];
  __shared__ float ebuf[2 * 64 * 17];        // k-phase combine, stride 17
  int t = threadIdx.x;
  int m0 = blockIdx.y * 32, n0 = blockIdx.x * 64;
  int wave = t >> 6, lane = t & 63;
  int h = wave & 1;            // n-half
  int p = wave >> 1;           // k-phase
  int l31 = lane & 31, l5 = lane >> 5;
  int srow = t >> 3, skc = (t & 7) * 8;      // staging: 32 rows x 64 cols

  f32x16 acc;
#pragma unroll
  for (int q = 0; q < 16; ++q) acc[q] = 0.f;

  const unsigned short* Ap = A + (size_t)(m0 + srow) * Kp + skc;
  const unsigned short* Bp = Bt + (size_t)(n0 + srow) * Kp + skc;
  size_t rstep = 32 * (size_t)Kp;

  u16x8 pa0 = *(const u16x8*)(Ap);
  u16x8 pb0 = *(const u16x8*)(Bp);
  u16x8 pb1 = *(const u16x8*)(Bp + rstep);

  for (int k0 = 0; k0 < Kp; k0 += 64) {
    *(u16x8*)&As[srow][skc]      = pa0;
    *(u16x8*)&Bs[srow][skc]      = pb0;
    *(u16x8*)&Bs[srow + 32][skc] = pb1;
    __syncthreads();
    if (k0 + 64 < Kp) {
      pa0 = *(const u16x8*)(Ap + k0 + 64);
      pb0 = *(const u16x8*)(Bp + k0 + 64);
      pb1 = *(const u16x8*)(Bp + k0 + 64 + rstep);
    }
    int kb = p * 32 + l5 * 8;
    {
      bf16x8 av = *(const bf16x8*)&As[l31][kb];
      bf16x8 bv = *(const bf16x8*)&Bs[h * 32 + l31][kb];
      acc = __builtin_amdgcn_mfma_f32_32x32x16_bf16(av, bv, acc, 0, 0, 0);
    }
    {
      bf16x8 av = *(const bf16x8*)&As[l31][kb + 16];
      bf16x8 bv = *(const bf16x8*)&Bs[h * 32 + l31][kb + 16];
      acc = __builtin_amdgcn_mfma_f32_32x32x16_bf16(av, bv, acc, 0, 0, 0);
    }
    __syncthreads();
  }

  // combine k-phases: p=1 publishes, p=0 adds + stores + stats
  float* eb = ebuf + (size_t)(h * 64 + lane) * 17;
  if (p == 1) {
#pragma unroll
    for (int r = 0; r < 16; ++r) eb[r] = acc[r];
  }
  __syncthreads();
  if (p == 0) {
    float s = 0.f, ss = 0.f;
#pragma unroll
    for (int r = 0; r < 16; ++r) {
      float v = acc[r] + eb[r];
      // C/D 32x32: col=lane&31, row=(r&3)+8*(r>>2)+4*(lane>>5)
      int row = m0 + (r & 3) + 8 * (r >> 2) + 4 * l5;
      C[(size_t)row * N + n0 + h * 32 + l31] = v;
      s += v;
      ss = fmaf(v, v, ss);
    }
    s  += __shfl_down(s, 32, 64);
    ss += __shfl_down(ss, 32, 64);
    if (lane < 32) {
      atomicAdd(&sum[n0 + h * 32 + lane], s);
      atomicAdd(&sq[n0 + h * 32 + lane], ss);
    }
  }
}

// ---------------------------------------------------------------------------
// GEMM2: A = t1 fp32, BN1+ReLU applied during LDS staging (-> bf16);
// B = W2bT bf16. Fused BN2 stats. 32x32 tile (grid 512 = 2 blocks/CU),
// 4 waves each 16x16. BN1 scale/shift precomputed once per block into
// LDS tables (broadcast reads, conflict-free).
// ---------------------------------------------------------------------------
__global__ __launch_bounds__(256) void gemm2_kernel(
    const float* __restrict__ A,             // [M][Kp] fp32 (t1, pre-BN)
    const unsigned short* __restrict__ Bt,   // [N][Kp] bf16
    float* __restrict__ C, const float* __restrict__ sum1,
    const float* __restrict__ sq1, const float* __restrict__ gam1,
    const float* __restrict__ bet1, float* __restrict__ sum2,
    float* __restrict__ sq2, int M, int N, int Kp) {
  __shared__ unsigned short As[32][72];
  __shared__ unsigned short Bs[32][72];
  __shared__ float sc1s[NH1], sh1s[NH1];     // 8 KB BN1 coef tables
  int t = threadIdx.x;
  int m0 = blockIdx.y * 32, n0 = blockIdx.x * 32;
  int wave = t >> 6, lane = t & 63;
  int wm = (wave >> 1) * 16, wn = (wave & 1) * 16;
  int fm = lane & 15, fk = (lane >> 4) * 8;
  int srow = t >> 3, skc = (t & 7) * 8;    // srow 0..31

  for (int k = t; k < Kp; k += 256) {      // once per block: 4 rsqrt/thread
    float mu  = sum1[k] * (1.f / NB);
    float var = sq1[k] * (1.f / NB) - mu * mu;
    float scv = gam1[k] * rsqrtf(var + EPSV);
    sc1s[k] = scv;
    sh1s[k] = fmaf(-mu, scv, bet1[k]);
  }

  f32x4 acc = (f32x4){0.f, 0.f, 0.f, 0.f};

  const float* Ap = A + (size_t)(m0 + srow) * Kp + skc;
  const unsigned short* Bp = Bt + (size_t)(n0 + srow) * Kp + skc;

  f32x4 pa0 = *(const f32x4*)(Ap);
  f32x4 pa1 = *(const f32x4*)(Ap + 4);
  u16x8 pb0 = *(const u16x8*)(Bp);
  __syncthreads();                          // coef tables ready

  for (int k0 = 0; k0 < Kp; k0 += 64) {
    // BN1 scale/shift from LDS (8 distinct 16B groups/wave -> broadcast)
    f32x4 scl = *(const f32x4*)&sc1s[k0 + skc];
    f32x4 sch = *(const f32x4*)&sc1s[k0 + skc + 4];
    f32x4 shl = *(const f32x4*)&sh1s[k0 + skc];
    f32x4 shh = *(const f32x4*)&sh1s[k0 + skc + 4];
    u16x8 a0;
#pragma unroll
    for (int i = 0; i < 4; ++i) {
      a0[i]     = f2bf(fmaxf(fmaf(pa0[i], scl[i], shl[i]), 0.f));
      a0[i + 4] = f2bf(fmaxf(fmaf(pa1[i], sch[i], shh[i]), 0.f));
    }
    *(u16x8*)&As[srow][skc] = a0;
    *(u16x8*)&Bs[srow][skc] = pb0;
    __syncthreads();
    if (k0 + 64 < Kp) {
      pa0 = *(const f32x4*)(Ap + k0 + 64);
      pa1 = *(const f32x4*)(Ap + k0 + 64 + 4);
      pb0 = *(const u16x8*)(Bp + k0 + 64);
    }
#pragma unroll
    for (int s = 0; s < 2; ++s) {
      bf16x8 af = *(const bf16x8*)&As[wm + fm][s * 32 + fk];
      bf16x8 bf = *(const bf16x8*)&Bs[wn + fm][s * 32 + fk];
      acc = __builtin_amdgcn_mfma_f32_16x16x32_bf16(af, bf, acc, 0, 0, 0);
    }
    __syncthreads();
  }

  int crow = (lane >> 4) * 4, ccol = lane & 15;
  float s = 0.f, ss = 0.f;
#pragma unroll
  for (int r = 0; r < 4; ++r) {
    float v = acc[r];
    int m = m0 + wm + crow + r;
    int n = n0 + wn + ccol;
    C[(size_t)m * N + n] = v;
    s += v;
    ss = fmaf(v, v, ss);
  }
  s  += __shfl_down(s, 32, 64);  s  += __shfl_down(s, 16, 64);
  ss += __shfl_down(ss, 32, 64); ss += __shfl_down(ss, 16, 64);
  if (lane < 16) {
    atomicAdd(&sum2[n0 + wn + lane], s);
    atomicAdd(&sq2[n0 + wn + lane], ss);
  }
}

// ---------------------------------------------------------------------------
// Final: BN2(inline)+ReLU on t2 row, main head from LDS-staged Wout,
// residual from prep's partials, softmax. Block per row, all 256 threads.
// ---------------------------------------------------------------------------
__global__ __launch_bounds__(256) void final_kernel(
    const float* __restrict__ t2, const float* __restrict__ sum2,
    const float* __restrict__ sq2, const float* __restrict__ gam2,
    const float* __restrict__ bet2, const float* __restrict__ rp,
    const float* __restrict__ Wout, const float* __restrict__ bout,
    const float* __restrict__ bres, float* __restrict__ out) {
  __shared__ __attribute__((aligned(16))) float wl[NH2 * NC];   // 20 KB
  __shared__ float red[4][NC];
  __shared__ float logits[NC];
  int b = blockIdx.x;
  int t = threadIdx.x;

  // stage Wout coalesced: 1280 float4 / 256 threads = 5 each
  const float4* wsrc = (const float4*)Wout;
  float4* wdst = (float4*)wl;
#pragma unroll
  for (int i = 0; i < (NH2 * NC / 4) / 256; ++i)
    wdst[t + i * 256] = wsrc[t + i * 256];
  __syncthreads();

  float acc[NC] = {};
#pragma unroll
  for (int half = 0; half < 2; ++half) {
    int h = t + half * 256;
    float raw = t2[(size_t)b * NH2 + h];
    float mu  = sum2[h] * (1.f / NB);
    float var = sq2[h] * (1.f / NB) - mu * mu;
    float scv = gam2[h] * rsqrtf(var + EPSV);
    float hr  = fmaxf(fmaf(raw, scv, fmaf(-mu, scv, bet2[h])), 0.f);
    const float* wrow = &wl[h * NC];
#pragma unroll
    for (int c = 0; c < NC; ++c) acc[c] = fmaf(hr, wrow[c], acc[c]);
  }

  int lane = t & 63, wave = t >> 6;
#pragma unroll
  for (int c = 0; c < NC; ++c) {
    float v = acc[c];
    for (int off = 32; off > 0; off >>= 1) v += __shfl_down(v, off, 64);
    if (lane == 0) red[wave][c] = v;
  }
  __syncthreads();
  if (t < NC) {
    float v = red[0][t] + red[1][t] + red[2][t] + red[3][t] + bout[t] + bres[t];
    const float* rpb = rp + (size_t)b * (10 * NC);
#pragma unroll
    for (int kb = 0; kb < 10; ++kb) v += rpb[kb * NC + t];
    logits[t] = v;
  }
  __syncthreads();
  if (t == 0) {
    float mx = logits[0];
#pragma unroll
    for (int c = 1; c < NC; ++c) mx = fmaxf(mx, logits[c]);
    float e[NC], s = 0.f;
#pragma unroll
    for (int c = 0; c < NC; ++c) { e[c] = expf(logits[c] - mx); s += e[c]; }
    float inv = 1.f / s;
#pragma unroll
    for (int c = 0; c < NC; ++c) out[(size_t)b * NC + c] = e[c] * inv;
  }
}

// ---------------------------------------------------------------------------
extern "C" void kernel_launch(void* const* d_in, const int* in_sizes, int n_in,
                              void* d_out, int out_size, void* d_ws, size_t ws_size,
                              hipStream_t stream) {
  const float* x      = (const float*)d_in[0];
  const float* gw     = (const float*)d_in[1];
  const float* gb     = (const float*)d_in[2];
  const float* W1     = (const float*)d_in[3];
  const float* gamma1 = (const float*)d_in[5];
  const float* beta1  = (const float*)d_in[6];
  const float* W2     = (const float*)d_in[7];
  const float* gamma2 = (const float*)d_in[9];
  const float* beta2  = (const float*)d_in[10];
  const float* Wout   = (const float*)d_in[11];
  const float* bout   = (const float*)d_in[12];
  const float* Wres   = (const float*)d_in[13];
  const float* bres   = (const float*)d_in[14];
  float* out = (float*)d_out;

  char* p = (char*)d_ws;
  unsigned short* g_bf = (unsigned short*)p; p += (size_t)NB * KP * 2;    // 4 MB
  unsigned short* W1bT = (unsigned short*)p; p += (size_t)NH1 * KP * 2;   // 4 MB
  unsigned short* W2bT = (unsigned short*)p; p += (size_t)NH2 * NH1 * 2;  // 1 MB
  float* t1 = (float*)p; p += (size_t)NB * NH1 * 4;                       // 4 MB
  float* t2 = (float*)p; p += (size_t)NB * NH2 * 4;                       // 2 MB
  float* stats = (float*)p; p += 3072 * 4;
  float* rp = (float*)p; p += (size_t)NB * 10 * NC * 4;                   // 400 KB
  float* sum1 = stats, *sq1 = stats + 1024, *sum2 = stats + 2048, *sq2 = stats + 2560;

  // gene (amortized over RB rows) + weight-transpose + stats-zero
  prep_kernel<<<dim3(128, 16), 256, 0, stream>>>(x, gw, gb, g_bf,
                                                 W1, W1bT, W2, W2bT,
                                                 Wres, rp, stats);

  gemm1_kernel<<<dim3(NH1 / 64, NB / 32), 256, 0, stream>>>(
      g_bf, W1bT, t1, sum1, sq1, NB, NH1, KP);

  gemm2_kernel<<<dim3(NH2 / 32, NB / 32), 256, 0, stream>>>(
      t1, W2bT, t2, sum1, sq1, gamma1, beta1, sum2, sq2, NB, NH2, NH1);

  final_kernel<<<NB, 256, 0, stream>>>(t2, sum2, sq2, gamma2, beta2, rp,
                                       Wout, bout, bres, out);
}

// Round 5
// 359.761 us; speedup vs baseline: 1.0818x; 1.0020x over previous
//
#include <hip/hip_runtime.h>
#include <math.h>

#define NB   1024
#define NG   2000
#define NGS  25
#define KP   2048   // K padded to multiple of 64 for MFMA GEMM1
#define NH1  1024
#define NH1X 1088   // NH1 + 64: rows 1024..1033 hold Wres^T, rest zero (R10)
#define NH2  512
#define NC   10
#define EPSV 1e-5f
#define GPB  200    // gene groups per block
#define RB   8      // batch rows per gene block

// R11 == R10 resubmit (R10 bench was an infra failure: container acquire
// died twice; no counters). Audit found no hazards; st[] zero-init added.
// R10: prep serialization attack. R9 post-mortem: prep ~105us in R7/R8/R9
// regardless of traffic pattern (R8 PMC: hbm 11%, VALU 10%, occ 44% --
// nothing busy => latency/DS-pipe bound, not BW). Changes:
// (a) prep gene path double-buffers the x stage (xs[2]): next row's loads
//     issue after the barrier and land under the current dot; 1 barrier
//     per round (was 3), no exposed HBM latency after prologue.
// (b) residual head (g @ Wres) moved into gemm1 as an MFMA n-tile:
//     Wres^T(bf16) = rows 1024..1087 of W1bT (NH1X), gemm1 grid.x 17,
//     extra tile writes rpx[b][0..63], skips BN stats. Kills prep's
//     480-shuffle/block reduce + Wres stage + rp machinery entirely.
// Timed-region model: ~240us harness poison fills (fixed) + kernels.

typedef __attribute__((ext_vector_type(8)))  __bf16 bf16x8;
typedef __attribute__((ext_vector_type(4)))  float  f32x4;
typedef __attribute__((ext_vector_type(16))) float  f32x16;
typedef __attribute__((ext_vector_type(8)))  unsigned short u16x8;

__device__ __forceinline__ unsigned short f2bf(float f) {
  union { float f; unsigned u; } v; v.f = f;
  return (unsigned short)((v.u + 0x7fffu + ((v.u >> 16) & 1u)) >> 16);
}

// ---------------------------------------------------------------------------
// Prep + gene dispatch. grid (128, 16):
//   y < 10 : gene block: gene-chunk y (200 groups), rows [x*RB, x*RB+RB),
//            double-buffered x staging, dot only (no residual work).
//   y >= 10: px = (y-10)*128 + x:
//            px<512 -> convT W1 tile; [512,640) -> convT W2 tile;
//            [640,672) -> Wres^T into W1bT rows 1024..1087;
//            px==672 -> zero BN stats; else idle.
// ---------------------------------------------------------------------------
__global__ __launch_bounds__(256) void prep_kernel(
    const float* __restrict__ x, const float* __restrict__ gw,
    const float* __restrict__ gb, unsigned short* __restrict__ g_bf,
    const float* __restrict__ W1, unsigned short* __restrict__ W1bT,
    const float* __restrict__ W2, unsigned short* __restrict__ W2bT,
    const float* __restrict__ Wres, float* __restrict__ stats) {
  __shared__ __attribute__((aligned(16))) float xs[2][GPB * NGS];  // 40 KB
  int t = threadIdx.x;

  if (blockIdx.y < 10) {                 // ---- gene path
    int blk = blockIdx.y;
    int b0 = blockIdx.x * RB;
    const size_t chunk_off = (size_t)blk * (GPB * NGS);

    // issue row-0 x loads immediately (overlap with gw staging below)
    float4 st[5];
#pragma unroll
    for (int j = 0; j < 5; ++j) st[j] = make_float4(0.f, 0.f, 0.f, 0.f);
    {
      const float4* s0 = (const float4*)(x + (size_t)b0 * (NG * NGS) + chunk_off);
#pragma unroll
      for (int j = 0; j < 5; ++j) {
        int i = t + j * 256;
        if (i < (GPB * NGS) / 4) st[j] = s0[i];
      }
    }
    // stage gw chunk (20 KB) coalesced into xs[0], then copy to registers
    const float4* gsrc = (const float4*)(gw + chunk_off);
    float4* xd0 = (float4*)xs[0];
    for (int i = t; i < (GPB * NGS) / 4; i += 256) xd0[i] = gsrc[i];
    __syncthreads();
    float gwr[NGS];
    float gbv = 0.f;
    int gi = blk * GPB + t;
    if (t < GPB) {
#pragma unroll
      for (int k = 0; k < NGS; ++k) gwr[k] = xs[0][t * NGS + k];
      gbv = gb[gi];
    }
    __syncthreads();                      // xs[0] free for round 0

    for (int r = 0; r < RB; ++r) {
      float* xc = xs[r & 1];
      float4* xdc = (float4*)xc;
#pragma unroll
      for (int j = 0; j < 5; ++j) {       // publish prefetched row r
        int i = t + j * 256;
        if (i < (GPB * NGS) / 4) xdc[i] = st[j];
      }
      __syncthreads();                    // row r visible to all
      if (r + 1 < RB) {                   // issue row r+1 loads; they land
        const float4* sn = (const float4*) //  under the dot below
            (x + (size_t)(b0 + r + 1) * (NG * NGS) + chunk_off);
#pragma unroll
        for (int j = 0; j < 5; ++j) {
          int i = t + j * 256;
          if (i < (GPB * NGS) / 4) st[j] = sn[i];
        }
      }
      int b = b0 + r;
      if (t < GPB) {
        float acc = 0.f;
        const float* xp = xc + t * NGS;   // stride-25: 2 lanes/bank, free
#pragma unroll
        for (int k = 0; k < NGS; ++k) acc = fmaf(xp[k], gwr[k], acc);
        g_bf[(size_t)b * KP + gi] = f2bf(fmaxf(acc + gbv, 0.f));
      } else if (blk == 9 && t < GPB + (KP - NG)) {
        g_bf[(size_t)b * KP + NG + (t - GPB)] = 0;   // zero-pad 2000..2047
      }
      // no trailing barrier: round r+1 writes xs[(r+1)&1]; last reads of
      // that buffer (round r-1) are sealed by this round's barrier.
    }
    return;
  }

  // ---- prep path (y >= 10)
  int px = (blockIdx.y - 10) * 128 + blockIdx.x;
  if (px == 672) {                       // zero BN stats (3072 floats)
    for (int i = t; i < 3072; i += 256) stats[i] = 0.f;
    return;
  }
  if (px > 672) return;
  const float* src; unsigned short* dst; int K, N, Kpad, k0, n0;
  int wres_mode = 0;
  if (px < 512)      { src = W1; dst = W1bT; K = NG;  N = NH1; Kpad = KP;
                       k0 = (px & 31) * 64; n0 = (px >> 5) * 64; }
  else if (px < 640) { int xi = px - 512;
                       src = W2; dst = W2bT; K = NH1; N = NH2; Kpad = NH1;
                       k0 = (xi & 15) * 64; n0 = (xi >> 4) * 64; }
  else               { int xi = px - 640;  // Wres^T -> W1bT rows 1024..1087
                       src = Wres; dst = W1bT; K = NG; N = NC; Kpad = KP;
                       k0 = xi * 64; n0 = 1024; wres_mode = 1; }

  unsigned short (*ts)[72] = (unsigned short (*)[72])xs;   // 64x72 = 9.2 KB
  int c4 = (t & 15) * 4;
  int r  = t >> 4;
  for (int rr = r; rr < 64; rr += 16) {
    int k = k0 + rr;
    float v[4] = {0.f, 0.f, 0.f, 0.f};
    if (!wres_mode) {
      if (k < K) {
        float4 q = *(const float4*)&src[(size_t)k * N + n0 + c4];
        v[0] = q.x; v[1] = q.y; v[2] = q.z; v[3] = q.w;
      }
    } else {
      if (k < K) {
#pragma unroll
        for (int i = 0; i < 4; ++i)
          if (c4 + i < NC) v[i] = src[(size_t)k * NC + c4 + i];
      }
    }
    ts[rr][c4 + 0] = f2bf(v[0]); ts[rr][c4 + 1] = f2bf(v[1]);
    ts[rr][c4 + 2] = f2bf(v[2]); ts[rr][c4 + 3] = f2bf(v[3]);
  }
  __syncthreads();
  int rr8 = (t & 7) * 8;
  int cc  = t >> 3;
  for (int c = cc; c < 64; c += 32) {
    u16x8 val;
#pragma unroll
    for (int i = 0; i < 8; ++i) val[i] = ts[rr8 + i][c];
    *(u16x8*)&dst[(size_t)(n0 + c) * Kpad + k0 + rr8] = val;
  }
}

// ---------------------------------------------------------------------------
// GEMM1: t1(fp32) = A(bf16)[M][Kp] * Bt(bf16)[NX][Kp]^T, fused BN1 stats.
// 32x64 block tile, 32x32x16 MFMA, grid (17, 32): n-tiles 0..15 -> t1 +
// stats; n-tile 16 -> residual head (Wres^T rows) -> rpx[b][0..63].
// 4 waves: h = n-half, p = k-phase; combine via stride-17 LDS buffer.
// ---------------------------------------------------------------------------
__global__ __launch_bounds__(256) void gemm1_kernel(
    const unsigned short* __restrict__ A,    // [M][Kp]
    const unsigned short* __restrict__ Bt,   // [NX][Kp]
    float* __restrict__ C, float* __restrict__ sum, float* __restrict__ sq,
    float* __restrict__ rpx, int M, int N, int Kp) {
  __shared__ unsigned short As[32][68];      // pitch 34 dw (== 2 mod 32)
  __shared__ unsigned short Bs[64][68];
  __shared__ float ebuf[2 * 64 * 17];        // k-phase combine, stride 17
  int t = threadIdx.x;
  int m0 = blockIdx.y * 32, n0 = blockIdx.x * 64;
  int wave = t >> 6, lane = t & 63;
  int h = wave & 1;            // n-half
  int p = wave >> 1;           // k-phase
  int l31 = lane & 31, l5 = lane >> 5;
  int srow = t >> 3, skc = (t & 7) * 8;      // staging: 32 rows x 64 cols

  f32x16 acc;
#pragma unroll
  for (int q = 0; q < 16; ++q) acc[q] = 0.f;

  const unsigned short* Ap = A + (size_t)(m0 + srow) * Kp + skc;
  const unsigned short* Bp = Bt + (size_t)(n0 + srow) * Kp + skc;
  size_t rstep = 32 * (size_t)Kp;

  u16x8 pa0 = *(const u16x8*)(Ap);
  u16x8 pb0 = *(const u16x8*)(Bp);
  u16x8 pb1 = *(const u16x8*)(Bp + rstep);

  for (int k0 = 0; k0 < Kp; k0 += 64) {
    *(u16x8*)&As[srow][skc]      = pa0;
    *(u16x8*)&Bs[srow][skc]      = pb0;
    *(u16x8*)&Bs[srow + 32][skc] = pb1;
    __syncthreads();
    if (k0 + 64 < Kp) {
      pa0 = *(const u16x8*)(Ap + k0 + 64);
      pb0 = *(const u16x8*)(Bp + k0 + 64);
      pb1 = *(const u16x8*)(Bp + k0 + 64 + rstep);
    }
    int kb = p * 32 + l5 * 8;
    {
      bf16x8 av = *(const bf16x8*)&As[l31][kb];
      bf16x8 bv = *(const bf16x8*)&Bs[h * 32 + l31][kb];
      acc = __builtin_amdgcn_mfma_f32_32x32x16_bf16(av, bv, acc, 0, 0, 0);
    }
    {
      bf16x8 av = *(const bf16x8*)&As[l31][kb + 16];
      bf16x8 bv = *(const bf16x8*)&Bs[h * 32 + l31][kb + 16];
      acc = __builtin_amdgcn_mfma_f32_32x32x16_bf16(av, bv, acc, 0, 0, 0);
    }
    __syncthreads();
  }

  // combine k-phases: p=1 publishes, p=0 adds + stores + stats
  float* eb = ebuf + (size_t)(h * 64 + lane) * 17;
  if (p == 1) {
#pragma unroll
    for (int r = 0; r < 16; ++r) eb[r] = acc[r];
  }
  __syncthreads();
  if (p == 0) {
    float s = 0.f, ss = 0.f;
#pragma unroll
    for (int r = 0; r < 16; ++r) {
      float v = acc[r] + eb[r];
      // C/D 32x32: col=lane&31, row=(r&3)+8*(r>>2)+4*(lane>>5)
      int row = m0 + (r & 3) + 8 * (r >> 2) + 4 * l5;
      if (n0 < N) {
        C[(size_t)row * N + n0 + h * 32 + l31] = v;
        s += v;
        ss = fmaf(v, v, ss);
      } else {
        rpx[(size_t)row * 64 + h * 32 + l31] = v;   // residual head
      }
    }
    if (n0 < N) {
      s  += __shfl_down(s, 32, 64);
      ss += __shfl_down(ss, 32, 64);
      if (lane < 32) {
        atomicAdd(&sum[n0 + h * 32 + lane], s);
        atomicAdd(&sq[n0 + h * 32 + lane], ss);
      }
    }
  }
}

// ---------------------------------------------------------------------------
// GEMM2: A = t1 fp32, BN1+ReLU applied during LDS staging (-> bf16);
// B = W2bT bf16. Fused BN2 stats. 32x32 tile, 4 waves each 16x16.
// BN1 scale/shift precomputed once per block into LDS tables.
// ---------------------------------------------------------------------------
__global__ __launch_bounds__(256) void gemm2_kernel(
    const float* __restrict__ A,             // [M][Kp] fp32 (t1, pre-BN)
    const unsigned short* __restrict__ Bt,   // [N][Kp] bf16
    float* __restrict__ C, const float* __restrict__ sum1,
    const float* __restrict__ sq1, const float* __restrict__ gam1,
    const float* __restrict__ bet1, float* __restrict__ sum2,
    float* __restrict__ sq2, int M, int N, int Kp) {
  __shared__ unsigned short As[32][72];
  __shared__ unsigned short Bs[32][72];
  __shared__ float sc1s[NH1], sh1s[NH1];     // 8 KB BN1 coef tables
  int t = threadIdx.x;
  int m0 = blockIdx.y * 32, n0 = blockIdx.x * 32;
  int wave = t >> 6, lane = t & 63;
  int wm = (wave >> 1) * 16, wn = (wave & 1) * 16;
  int fm = lane & 15, fk = (lane >> 4) * 8;
  int srow = t >> 3, skc = (t & 7) * 8;    // srow 0..31

  for (int k = t; k < Kp; k += 256) {      // once per block: 4 rsqrt/thread
    float mu  = sum1[k] * (1.f / NB);
    float var = sq1[k] * (1.f / NB) - mu * mu;
    float scv = gam1[k] * rsqrtf(var + EPSV);
    sc1s[k] = scv;
    sh1s[k] = fmaf(-mu, scv, bet1[k]);
  }

  f32x4 acc = (f32x4){0.f, 0.f, 0.f, 0.f};

  const float* Ap = A + (size_t)(m0 + srow) * Kp + skc;
  const unsigned short* Bp = Bt + (size_t)(n0 + srow) * Kp + skc;

  f32x4 pa0 = *(const f32x4*)(Ap);
  f32x4 pa1 = *(const f32x4*)(Ap + 4);
  u16x8 pb0 = *(const u16x8*)(Bp);
  __syncthreads();                          // coef tables ready

  for (int k0 = 0; k0 < Kp; k0 += 64) {
    f32x4 scl = *(const f32x4*)&sc1s[k0 + skc];
    f32x4 sch = *(const f32x4*)&sc1s[k0 + skc + 4];
    f32x4 shl = *(const f32x4*)&sh1s[k0 + skc];
    f32x4 shh = *(const f32x4*)&sh1s[k0 + skc + 4];
    u16x8 a0;
#pragma unroll
    for (int i = 0; i < 4; ++i) {
      a0[i]     = f2bf(fmaxf(fmaf(pa0[i], scl[i], shl[i]), 0.f));
      a0[i + 4] = f2bf(fmaxf(fmaf(pa1[i], sch[i], shh[i]), 0.f));
    }
    *(u16x8*)&As[srow][skc] = a0;
    *(u16x8*)&Bs[srow][skc] = pb0;
    __syncthreads();
    if (k0 + 64 < Kp) {
      pa0 = *(const f32x4*)(Ap + k0 + 64);
      pa1 = *(const f32x4*)(Ap + k0 + 64 + 4);
      pb0 = *(const u16x8*)(Bp + k0 + 64);
    }
#pragma unroll
    for (int s = 0; s < 2; ++s) {
      bf16x8 af = *(const bf16x8*)&As[wm + fm][s * 32 + fk];
      bf16x8 bf = *(const bf16x8*)&Bs[wn + fm][s * 32 + fk];
      acc = __builtin_amdgcn_mfma_f32_16x16x32_bf16(af, bf, acc, 0, 0, 0);
    }
    __syncthreads();
  }

  int crow = (lane >> 4) * 4, ccol = lane & 15;
  float s = 0.f, ss = 0.f;
#pragma unroll
  for (int r = 0; r < 4; ++r) {
    float v = acc[r];
    int m = m0 + wm + crow + r;
    int n = n0 + wn + ccol;
    C[(size_t)m * N + n] = v;
    s += v;
    ss = fmaf(v, v, ss);
  }
  s  += __shfl_down(s, 32, 64);  s  += __shfl_down(s, 16, 64);
  ss += __shfl_down(ss, 32, 64); ss += __shfl_down(ss, 16, 64);
  if (lane < 16) {
    atomicAdd(&sum2[n0 + wn + lane], s);
    atomicAdd(&sq2[n0 + wn + lane], ss);
  }
}

// ---------------------------------------------------------------------------
// Final: BN2(inline)+ReLU on t2 row, main head from LDS-staged Wout,
// residual from gemm1's rpx, softmax. Block per row, all 256 threads.
// ---------------------------------------------------------------------------
__global__ __launch_bounds__(256) void final_kernel(
    const float* __restrict__ t2, const float* __restrict__ sum2,
    const float* __restrict__ sq2, const float* __restrict__ gam2,
    const float* __restrict__ bet2, const float* __restrict__ rpx,
    const float* __restrict__ Wout, const float* __restrict__ bout,
    const float* __restrict__ bres, float* __restrict__ out) {
  __shared__ __attribute__((aligned(16))) float wl[NH2 * NC];   // 20 KB
  __shared__ float red[4][NC];
  __shared__ float logits[NC];
  int b = blockIdx.x;
  int t = threadIdx.x;

  // stage Wout coalesced: 1280 float4 / 256 threads = 5 each
  const float4* wsrc = (const float4*)Wout;
  float4* wdst = (float4*)wl;
#pragma unroll
  for (int i = 0; i < (NH2 * NC / 4) / 256; ++i)
    wdst[t + i * 256] = wsrc[t + i * 256];
  __syncthreads();

  float acc[NC] = {};
#pragma unroll
  for (int half = 0; half < 2; ++half) {
    int h = t + half * 256;
    float raw = t2[(size_t)b * NH2 + h];
    float mu  = sum2[h] * (1.f / NB);
    float var = sq2[h] * (1.f / NB) - mu * mu;
    float scv = gam2[h] * rsqrtf(var + EPSV);
    float hr  = fmaxf(fmaf(raw, scv, fmaf(-mu, scv, bet2[h])), 0.f);
    const float* wrow = &wl[h * NC];
#pragma unroll
    for (int c = 0; c < NC; ++c) acc[c] = fmaf(hr, wrow[c], acc[c]);
  }

  int lane = t & 63, wave = t >> 6;
#pragma unroll
  for (int c = 0; c < NC; ++c) {
    float v = acc[c];
    for (int off = 32; off > 0; off >>= 1) v += __shfl_down(v, off, 64);
    if (lane == 0) red[wave][c] = v;
  }
  __syncthreads();
  if (t < NC) {
    logits[t] = red[0][t] + red[1][t] + red[2][t] + red[3][t] +
                bout[t] + bres[t] + rpx[(size_t)b * 64 + t];
  }
  __syncthreads();
  if (t == 0) {
    float mx = logits[0];
#pragma unroll
    for (int c = 1; c < NC; ++c) mx = fmaxf(mx, logits[c]);
    float e[NC], s = 0.f;
#pragma unroll
    for (int c = 0; c < NC; ++c) { e[c] = expf(logits[c] - mx); s += e[c]; }
    float inv = 1.f / s;
#pragma unroll
    for (int c = 0; c < NC; ++c) out[(size_t)b * NC + c] = e[c] * inv;
  }
}

// ---------------------------------------------------------------------------
extern "C" void kernel_launch(void* const* d_in, const int* in_sizes, int n_in,
                              void* d_out, int out_size, void* d_ws, size_t ws_size,
                              hipStream_t stream) {
  const float* x      = (const float*)d_in[0];
  const float* gw     = (const float*)d_in[1];
  const float* gb     = (const float*)d_in[2];
  const float* W1     = (const float*)d_in[3];
  const float* gamma1 = (const float*)d_in[5];
  const float* beta1  = (const float*)d_in[6];
  const float* W2     = (const float*)d_in[7];
  const float* gamma2 = (const float*)d_in[9];
  const float* beta2  = (const float*)d_in[10];
  const float* Wout   = (const float*)d_in[11];
  const float* bout   = (const float*)d_in[12];
  const float* Wres   = (const float*)d_in[13];
  const float* bres   = (const float*)d_in[14];
  float* out = (float*)d_out;

  char* p = (char*)d_ws;
  unsigned short* g_bf = (unsigned short*)p; p += (size_t)NB * KP * 2;     // 4 MB
  unsigned short* W1bT = (unsigned short*)p; p += (size_t)NH1X * KP * 2;   // 4.25 MB
  unsigned short* W2bT = (unsigned short*)p; p += (size_t)NH2 * NH1 * 2;   // 1 MB
  float* t1 = (float*)p; p += (size_t)NB * NH1 * 4;                        // 4 MB
  float* t2 = (float*)p; p += (size_t)NB * NH2 * 4;                        // 2 MB
  float* stats = (float*)p; p += 3072 * 4;
  float* rpx = (float*)p; p += (size_t)NB * 64 * 4;                        // 256 KB
  float* sum1 = stats, *sq1 = stats + 1024, *sum2 = stats + 2048, *sq2 = stats + 2560;

  // gene (dbuf over RB rows) + weight/Wres transpose + stats-zero
  prep_kernel<<<dim3(128, 16), 256, 0, stream>>>(x, gw, gb, g_bf,
                                                 W1, W1bT, W2, W2bT,
                                                 Wres, stats);

  gemm1_kernel<<<dim3(NH1X / 64, NB / 32), 256, 0, stream>>>(
      g_bf, W1bT, t1, sum1, sq1, rpx, NB, NH1, KP);

  gemm2_kernel<<<dim3(NH2 / 32, NB / 32), 256, 0, stream>>>(
      t1, W2bT, t2, sum1, sq1, gamma1, beta1, sum2, sq2, NB, NH2, NH1);

  final_kernel<<<NB, 256, 0, stream>>>(t2, sum2, sq2, gamma2, beta2, rpx,
                                       Wout, bout, bres, out);
}

// Round 6
// 355.533 us; speedup vs baseline: 1.0946x; 1.0119x over previous
//
#include <hip/hip_runtime.h>
#include <math.h>

#define NB   1024
#define NG   2000
#define NGS  25
#define KP   2048   // K padded to multiple of 64 for MFMA GEMM1
#define NH1  1024
#define NH1X 1088   // NH1 + 64: rows 1024..1033 hold Wres^T, rest zero
#define NH2  512
#define NC   10
#define EPSV 1e-5f
#define GPB  200    // gene groups per block (50 per wave)
#define RB   8      // batch rows per gene block

// R12: barrier-free wave-autonomous gene path. Ledger: prep pinned at
// ~105us across 4 structures (R7/R8/R9/R11) while all throughput models
// say 35-45us and R8 PMC shows nothing busy. The never-removed invariant:
// block-wide __syncthreads + vmcnt(0) full drain before each LDS publish
// (compiler drains ALL in-flight loads at every barrier -- G5 structural
// stall, 8x/block x 1280 blocks). This round: each wave owns a private
// 5KB LDS slice (50 genes), NO barriers in the loop; same-wave DS
// ordering makes publish->dot->republish safe; per-register counted
// vmcnt lets each wave's next-row loads fly under its own dot; waves
// drift freely. A/B reg buffers, 2-row unrolled body (no reg rotate).
// If prep drops to ~45: coupling confirmed (total ~300). If null:
// coupling falsified -> pattern-intrinsic or attribution wrong.

typedef __attribute__((ext_vector_type(8)))  __bf16 bf16x8;
typedef __attribute__((ext_vector_type(4)))  float  f32x4;
typedef __attribute__((ext_vector_type(16))) float  f32x16;
typedef __attribute__((ext_vector_type(8)))  unsigned short u16x8;

__device__ __forceinline__ unsigned short f2bf(float f) {
  union { float f; unsigned u; } v; v.f = f;
  return (unsigned short)((v.u + 0x7fffu + ((v.u >> 16) & 1u)) >> 16);
}

// ---------------------------------------------------------------------------
// Prep + gene dispatch. grid (128, 16):
//   y < 10 : gene block: gene-chunk y (200 groups = 4 waves x 50), rows
//            [x*RB, x*RB+RB). Wave-private LDS slice, zero barriers.
//   y >= 10: px = (y-10)*128 + x:
//            px<512 -> convT W1 tile; [512,640) -> convT W2 tile;
//            [640,672) -> Wres^T into W1bT rows 1024..1087;
//            px==672 -> zero BN stats; else idle.
// ---------------------------------------------------------------------------
__global__ __launch_bounds__(256) void prep_kernel(
    const float* __restrict__ x, const float* __restrict__ gw,
    const float* __restrict__ gb, unsigned short* __restrict__ g_bf,
    const float* __restrict__ W1, unsigned short* __restrict__ W1bT,
    const float* __restrict__ W2, unsigned short* __restrict__ W2bT,
    const float* __restrict__ Wres, float* __restrict__ stats) {
  // 4 wave-private slices of 1284 floats (1252 used + pad) = 20.5 KB
  __shared__ __attribute__((aligned(16))) float xsl[4][1284];
  int t = threadIdx.x;

  if (blockIdx.y < 10) {                 // ---- gene path (wave-autonomous)
    int blk = blockIdx.y;
    int b0 = blockIdx.x * RB;
    int w = t >> 6, l = t & 63;
    int d = (w & 1) * 2;                 // window misalignment (floats)
    // wave's float window within a row: [blk*5000 + w*1250 - d, +1252)
    size_t wchunk = (size_t)blk * (GPB * NGS) + w * 1250 - d;  // %4 == 0
    float4* slice4 = (float4*)xsl[w];
    const float* xrd = xsl[w] + d;

    // issue gw window loads, then x row-0 loads (both in flight)
    float4 sg[5], stA[5], stB[5];
    const float4* gw4 = (const float4*)gw + (wchunk >> 2);
#pragma unroll
    for (int j = 0; j < 5; ++j) {
      int idx = l + j * 64;
      sg[j] = (idx < 313) ? gw4[idx] : make_float4(0.f, 0.f, 0.f, 0.f);
    }
    {
      const float4* x0 = (const float4*)x + (((size_t)b0 * (NG * NGS) + wchunk) >> 2);
#pragma unroll
      for (int j = 0; j < 5; ++j) {
        int idx = l + j * 64;
        stA[j] = (idx < 313) ? x0[idx] : make_float4(0.f, 0.f, 0.f, 0.f);
      }
    }
    // publish gw -> slice (waits only sg's vmcnt), copy to registers
#pragma unroll
    for (int j = 0; j < 5; ++j) {
      int idx = l + j * 64;
      if (idx < 313) slice4[idx] = sg[j];
    }
    float gwr[NGS];
    float gbv = 0.f;
    if (l < 50) {
#pragma unroll
      for (int k = 0; k < NGS; ++k) gwr[k] = xrd[l * 25 + k];
      gbv = gb[blk * GPB + w * 50 + l];
    }

    auto publish = [&](const float4* st) {
#pragma unroll
      for (int j = 0; j < 5; ++j) {
        int idx = l + j * 64;
        if (idx < 313) slice4[idx] = st[j];
      }
    };
    auto issue = [&](float4* st, int row) {
      const float4* xn = (const float4*)x + (((size_t)row * (NG * NGS) + wchunk) >> 2);
#pragma unroll
      for (int j = 0; j < 5; ++j) {
        int idx = l + j * 64;
        st[j] = (idx < 313) ? xn[idx] : make_float4(0.f, 0.f, 0.f, 0.f);
      }
    };
    auto dot = [&](int b) {
      if (l < 50) {
        float acc = 0.f;
#pragma unroll
        for (int k = 0; k < NGS; ++k) acc = fmaf(xrd[l * 25 + k], gwr[k], acc);
        g_bf[(size_t)b * KP + blk * GPB + w * 50 + l] =
            f2bf(fmaxf(acc + gbv, 0.f));
      } else if (blk == 9 && w == 0) {   // idle lanes zero-pad k 2000..2047
#pragma unroll
        for (int j = 0; j < 4; ++j) {
          int pp = (l - 50) + 14 * j;
          if (pp < KP - NG) g_bf[(size_t)b * KP + NG + pp] = 0;
        }
      }
    };

    // 2-row unrolled pipeline: publish(cur) ; issue(next) ; dot(cur)
#pragma unroll
    for (int rr = 0; rr < RB / 2; ++rr) {
      int rA = rr * 2;
      publish(stA);
      issue(stB, b0 + rA + 1);
      dot(b0 + rA);
      publish(stB);
      if (rA + 2 < RB) issue(stA, b0 + rA + 2);
      dot(b0 + rA + 1);
    }
    return;
  }

  // ---- prep path (y >= 10)
  int px = (blockIdx.y - 10) * 128 + blockIdx.x;
  if (px == 672) {                       // zero BN stats (3072 floats)
    for (int i = t; i < 3072; i += 256) stats[i] = 0.f;
    return;
  }
  if (px > 672) return;
  const float* src; unsigned short* dst; int K, N, Kpad, k0, n0;
  int wres_mode = 0;
  if (px < 512)      { src = W1; dst = W1bT; K = NG;  N = NH1; Kpad = KP;
                       k0 = (px & 31) * 64; n0 = (px >> 5) * 64; }
  else if (px < 640) { int xi = px - 512;
                       src = W2; dst = W2bT; K = NH1; N = NH2; Kpad = NH1;
                       k0 = (xi & 15) * 64; n0 = (xi >> 4) * 64; }
  else               { int xi = px - 640;  // Wres^T -> W1bT rows 1024..1087
                       src = Wres; dst = W1bT; K = NG; N = NC; Kpad = KP;
                       k0 = xi * 64; n0 = 1024; wres_mode = 1; }

  unsigned short (*ts)[72] = (unsigned short (*)[72])xsl;   // 9.2 KB alias
  int c4 = (t & 15) * 4;
  int r  = t >> 4;
  for (int rr = r; rr < 64; rr += 16) {
    int k = k0 + rr;
    float v[4] = {0.f, 0.f, 0.f, 0.f};
    if (!wres_mode) {
      if (k < K) {
        float4 q = *(const float4*)&src[(size_t)k * N + n0 + c4];
        v[0] = q.x; v[1] = q.y; v[2] = q.z; v[3] = q.w;
      }
    } else {
      if (k < K) {
#pragma unroll
        for (int i = 0; i < 4; ++i)
          if (c4 + i < NC) v[i] = src[(size_t)k * NC + c4 + i];
      }
    }
    ts[rr][c4 + 0] = f2bf(v[0]); ts[rr][c4 + 1] = f2bf(v[1]);
    ts[rr][c4 + 2] = f2bf(v[2]); ts[rr][c4 + 3] = f2bf(v[3]);
  }
  __syncthreads();
  int rr8 = (t & 7) * 8;
  int cc  = t >> 3;
  for (int c = cc; c < 64; c += 32) {
    u16x8 val;
#pragma unroll
    for (int i = 0; i < 8; ++i) val[i] = ts[rr8 + i][c];
    *(u16x8*)&dst[(size_t)(n0 + c) * Kpad + k0 + rr8] = val;
  }
}

// ---------------------------------------------------------------------------
// GEMM1: t1(fp32) = A(bf16)[M][Kp] * Bt(bf16)[NX][Kp]^T, fused BN1 stats.
// 32x64 block tile, 32x32x16 MFMA, grid (17, 32): n-tiles 0..15 -> t1 +
// stats; n-tile 16 -> residual head (Wres^T rows) -> rpx[b][0..63].
// 4 waves: h = n-half, p = k-phase; combine via stride-17 LDS buffer.
// ---------------------------------------------------------------------------
__global__ __launch_bounds__(256) void gemm1_kernel(
    const unsigned short* __restrict__ A,    // [M][Kp]
    const unsigned short* __restrict__ Bt,   // [NX][Kp]
    float* __restrict__ C, float* __restrict__ sum, float* __restrict__ sq,
    float* __restrict__ rpx, int M, int N, int Kp) {
  __shared__ unsigned short As[32][68];      // pitch 34 dw (== 2 mod 32)
  __shared__ unsigned short Bs[64][68];
  __shared__ float ebuf[2 * 64 * 17];        // k-phase combine, stride 17
  int t = threadIdx.x;
  int m0 = blockIdx.y * 32, n0 = blockIdx.x * 64;
  int wave = t >> 6, lane = t & 63;
  int h = wave & 1;            // n-half
  int p = wave >> 1;           // k-phase
  int l31 = lane & 31, l5 = lane >> 5;
  int srow = t >> 3, skc = (t & 7) * 8;      // staging: 32 rows x 64 cols

  f32x16 acc;
#pragma unroll
  for (int q = 0; q < 16; ++q) acc[q] = 0.f;

  const unsigned short* Ap = A + (size_t)(m0 + srow) * Kp + skc;
  const unsigned short* Bp = Bt + (size_t)(n0 + srow) * Kp + skc;
  size_t rstep = 32 * (size_t)Kp;

  u16x8 pa0 = *(const u16x8*)(Ap);
  u16x8 pb0 = *(const u16x8*)(Bp);
  u16x8 pb1 = *(const u16x8*)(Bp + rstep);

  for (int k0 = 0; k0 < Kp; k0 += 64) {
    *(u16x8*)&As[srow][skc]      = pa0;
    *(u16x8*)&Bs[srow][skc]      = pb0;
    *(u16x8*)&Bs[srow + 32][skc] = pb1;
    __syncthreads();
    if (k0 + 64 < Kp) {
      pa0 = *(const u16x8*)(Ap + k0 + 64);
      pb0 = *(const u16x8*)(Bp + k0 + 64);
      pb1 = *(const u16x8*)(Bp + k0 + 64 + rstep);
    }
    int kb = p * 32 + l5 * 8;
    {
      bf16x8 av = *(const bf16x8*)&As[l31][kb];
      bf16x8 bv = *(const bf16x8*)&Bs[h * 32 + l31][kb];
      acc = __builtin_amdgcn_mfma_f32_32x32x16_bf16(av, bv, acc, 0, 0, 0);
    }
    {
      bf16x8 av = *(const bf16x8*)&As[l31][kb + 16];
      bf16x8 bv = *(const bf16x8*)&Bs[h * 32 + l31][kb + 16];
      acc = __builtin_amdgcn_mfma_f32_32x32x16_bf16(av, bv, acc, 0, 0, 0);
    }
    __syncthreads();
  }

  // combine k-phases: p=1 publishes, p=0 adds + stores + stats
  float* eb = ebuf + (size_t)(h * 64 + lane) * 17;
  if (p == 1) {
#pragma unroll
    for (int r = 0; r < 16; ++r) eb[r] = acc[r];
  }
  __syncthreads();
  if (p == 0) {
    float s = 0.f, ss = 0.f;
#pragma unroll
    for (int r = 0; r < 16; ++r) {
      float v = acc[r] + eb[r];
      // C/D 32x32: col=lane&31, row=(r&3)+8*(r>>2)+4*(lane>>5)
      int row = m0 + (r & 3) + 8 * (r >> 2) + 4 * l5;
      if (n0 < N) {
        C[(size_t)row * N + n0 + h * 32 + l31] = v;
        s += v;
        ss = fmaf(v, v, ss);
      } else {
        rpx[(size_t)row * 64 + h * 32 + l31] = v;   // residual head
      }
    }
    if (n0 < N) {
      s  += __shfl_down(s, 32, 64);
      ss += __shfl_down(ss, 32, 64);
      if (lane < 32) {
        atomicAdd(&sum[n0 + h * 32 + lane], s);
        atomicAdd(&sq[n0 + h * 32 + lane], ss);
      }
    }
  }
}

// ---------------------------------------------------------------------------
// GEMM2: A = t1 fp32, BN1+ReLU applied during LDS staging (-> bf16);
// B = W2bT bf16. Fused BN2 stats. 32x32 tile, 4 waves each 16x16.
// BN1 scale/shift precomputed once per block into LDS tables.
// ---------------------------------------------------------------------------
__global__ __launch_bounds__(256) void gemm2_kernel(
    const float* __restrict__ A,             // [M][Kp] fp32 (t1, pre-BN)
    const unsigned short* __restrict__ Bt,   // [N][Kp] bf16
    float* __restrict__ C, const float* __restrict__ sum1,
    const float* __restrict__ sq1, const float* __restrict__ gam1,
    const float* __restrict__ bet1, float* __restrict__ sum2,
    float* __restrict__ sq2, int M, int N, int Kp) {
  __shared__ unsigned short As[32][72];
  __shared__ unsigned short Bs[32][72];
  __shared__ float sc1s[NH1], sh1s[NH1];     // 8 KB BN1 coef tables
  int t = threadIdx.x;
  int m0 = blockIdx.y * 32, n0 = blockIdx.x * 32;
  int wave = t >> 6, lane = t & 63;
  int wm = (wave >> 1) * 16, wn = (wave & 1) * 16;
  int fm = lane & 15, fk = (lane >> 4) * 8;
  int srow = t >> 3, skc = (t & 7) * 8;    // srow 0..31

  for (int k = t; k < Kp; k += 256) {      // once per block: 4 rsqrt/thread
    float mu  = sum1[k] * (1.f / NB);
    float var = sq1[k] * (1.f / NB) - mu * mu;
    float scv = gam1[k] * rsqrtf(var + EPSV);
    sc1s[k] = scv;
    sh1s[k] = fmaf(-mu, scv, bet1[k]);
  }

  f32x4 acc = (f32x4){0.f, 0.f, 0.f, 0.f};

  const float* Ap = A + (size_t)(m0 + srow) * Kp + skc;
  const unsigned short* Bp = Bt + (size_t)(n0 + srow) * Kp + skc;

  f32x4 pa0 = *(const f32x4*)(Ap);
  f32x4 pa1 = *(const f32x4*)(Ap + 4);
  u16x8 pb0 = *(const u16x8*)(Bp);
  __syncthreads();                          // coef tables ready

  for (int k0 = 0; k0 < Kp; k0 += 64) {
    f32x4 scl = *(const f32x4*)&sc1s[k0 + skc];
    f32x4 sch = *(const f32x4*)&sc1s[k0 + skc + 4];
    f32x4 shl = *(const f32x4*)&sh1s[k0 + skc];
    f32x4 shh = *(const f32x4*)&sh1s[k0 + skc + 4];
    u16x8 a0;
#pragma unroll
    for (int i = 0; i < 4; ++i) {
      a0[i]     = f2bf(fmaxf(fmaf(pa0[i], scl[i], shl[i]), 0.f));
      a0[i + 4] = f2bf(fmaxf(fmaf(pa1[i], sch[i], shh[i]), 0.f));
    }
    *(u16x8*)&As[srow][skc] = a0;
    *(u16x8*)&Bs[srow][skc] = pb0;
    __syncthreads();
    if (k0 + 64 < Kp) {
      pa0 = *(const f32x4*)(Ap + k0 + 64);
      pa1 = *(const f32x4*)(Ap + k0 + 64 + 4);
      pb0 = *(const u16x8*)(Bp + k0 + 64);
    }
#pragma unroll
    for (int s = 0; s < 2; ++s) {
      bf16x8 af = *(const bf16x8*)&As[wm + fm][s * 32 + fk];
      bf16x8 bf = *(const bf16x8*)&Bs[wn + fm][s * 32 + fk];
      acc = __builtin_amdgcn_mfma_f32_16x16x32_bf16(af, bf, acc, 0, 0, 0);
    }
    __syncthreads();
  }

  int crow = (lane >> 4) * 4, ccol = lane & 15;
  float s = 0.f, ss = 0.f;
#pragma unroll
  for (int r = 0; r < 4; ++r) {
    float v = acc[r];
    int m = m0 + wm + crow + r;
    int n = n0 + wn + ccol;
    C[(size_t)m * N + n] = v;
    s += v;
    ss = fmaf(v, v, ss);
  }
  s  += __shfl_down(s, 32, 64);  s  += __shfl_down(s, 16, 64);
  ss += __shfl_down(ss, 32, 64); ss += __shfl_down(ss, 16, 64);
  if (lane < 16) {
    atomicAdd(&sum2[n0 + wn + lane], s);
    atomicAdd(&sq2[n0 + wn + lane], ss);
  }
}

// ---------------------------------------------------------------------------
// Final: BN2(inline)+ReLU on t2 row, main head from LDS-staged Wout,
// residual from gemm1's rpx, softmax. Block per row, all 256 threads.
// ---------------------------------------------------------------------------
__global__ __launch_bounds__(256) void final_kernel(
    const float* __restrict__ t2, const float* __restrict__ sum2,
    const float* __restrict__ sq2, const float* __restrict__ gam2,
    const float* __restrict__ bet2, const float* __restrict__ rpx,
    const float* __restrict__ Wout, const float* __restrict__ bout,
    const float* __restrict__ bres, float* __restrict__ out) {
  __shared__ __attribute__((aligned(16))) float wl[NH2 * NC];   // 20 KB
  __shared__ float red[4][NC];
  __shared__ float logits[NC];
  int b = blockIdx.x;
  int t = threadIdx.x;

  // stage Wout coalesced: 1280 float4 / 256 threads = 5 each
  const float4* wsrc = (const float4*)Wout;
  float4* wdst = (float4*)wl;
#pragma unroll
  for (int i = 0; i < (NH2 * NC / 4) / 256; ++i)
    wdst[t + i * 256] = wsrc[t + i * 256];
  __syncthreads();

  float acc[NC] = {};
#pragma unroll
  for (int half = 0; half < 2; ++half) {
    int h = t + half * 256;
    float raw = t2[(size_t)b * NH2 + h];
    float mu  = sum2[h] * (1.f / NB);
    float var = sq2[h] * (1.f / NB) - mu * mu;
    float scv = gam2[h] * rsqrtf(var + EPSV);
    float hr  = fmaxf(fmaf(raw, scv, fmaf(-mu, scv, bet2[h])), 0.f);
    const float* wrow = &wl[h * NC];
#pragma unroll
    for (int c = 0; c < NC; ++c) acc[c] = fmaf(hr, wrow[c], acc[c]);
  }

  int lane = t & 63, wave = t >> 6;
#pragma unroll
  for (int c = 0; c < NC; ++c) {
    float v = acc[c];
    for (int off = 32; off > 0; off >>= 1) v += __shfl_down(v, off, 64);
    if (lane == 0) red[wave][c] = v;
  }
  __syncthreads();
  if (t < NC) {
    logits[t] = red[0][t] + red[1][t] + red[2][t] + red[3][t] +
                bout[t] + bres[t] + rpx[(size_t)b * 64 + t];
  }
  __syncthreads();
  if (t == 0) {
    float mx = logits[0];
#pragma unroll
    for (int c = 1; c < NC; ++c) mx = fmaxf(mx, logits[c]);
    float e[NC], s = 0.f;
#pragma unroll
    for (int c = 0; c < NC; ++c) { e[c] = expf(logits[c] - mx); s += e[c]; }
    float inv = 1.f / s;
#pragma unroll
    for (int c = 0; c < NC; ++c) out[(size_t)b * NC + c] = e[c] * inv;
  }
}

// ---------------------------------------------------------------------------
extern "C" void kernel_launch(void* const* d_in, const int* in_sizes, int n_in,
                              void* d_out, int out_size, void* d_ws, size_t ws_size,
                              hipStream_t stream) {
  const float* x      = (const float*)d_in[0];
  const float* gw     = (const float*)d_in[1];
  const float* gb     = (const float*)d_in[2];
  const float* W1     = (const float*)d_in[3];
  const float* gamma1 = (const float*)d_in[5];
  const float* beta1  = (const float*)d_in[6];
  const float* W2     = (const float*)d_in[7];
  const float* gamma2 = (const float*)d_in[9];
  const float* beta2  = (const float*)d_in[10];
  const float* Wout   = (const float*)d_in[11];
  const float* bout   = (const float*)d_in[12];
  const float* Wres   = (const float*)d_in[13];
  const float* bres   = (const float*)d_in[14];
  float* out = (float*)d_out;

  char* p = (char*)d_ws;
  unsigned short* g_bf = (unsigned short*)p; p += (size_t)NB * KP * 2;     // 4 MB
  unsigned short* W1bT = (unsigned short*)p; p += (size_t)NH1X * KP * 2;   // 4.25 MB
  unsigned short* W2bT = (unsigned short*)p; p += (size_t)NH2 * NH1 * 2;   // 1 MB
  float* t1 = (float*)p; p += (size_t)NB * NH1 * 4;                        // 4 MB
  float* t2 = (float*)p; p += (size_t)NB * NH2 * 4;                        // 2 MB
  float* stats = (float*)p; p += 3072 * 4;
  float* rpx = (float*)p; p += (size_t)NB * 64 * 4;                        // 256 KB
  float* sum1 = stats, *sq1 = stats + 1024, *sum2 = stats + 2048, *sq2 = stats + 2560;

  // gene (wave-autonomous, barrier-free) + weight/Wres transpose + stats
  prep_kernel<<<dim3(128, 16), 256, 0, stream>>>(x, gw, gb, g_bf,
                                                 W1, W1bT, W2, W2bT,
                                                 Wres, stats);

  gemm1_kernel<<<dim3(NH1X / 64, NB / 32), 256, 0, stream>>>(
      g_bf, W1bT, t1, sum1, sq1, rpx, NB, NH1, KP);

  gemm2_kernel<<<dim3(NH2 / 32, NB / 32), 256, 0, stream>>>(
      t1, W2bT, t2, sum1, sq1, gamma1, beta1, sum2, sq2, NB, NH2, NH1);

  final_kernel<<<NB, 256, 0, stream>>>(t2, sum2, sq2, gamma2, beta2, rpx,
                                       Wout, bout, bres, out);
}